// Round 4
// baseline (125.860 us; speedup 1.0000x reference)
//
#include <hip/hip_runtime.h>
#include <math.h>

// Problem constants (from reference)
constexpr int VOCAB = 100000;
constexpr int DIM   = 128;
constexpr int B     = 16384;
constexpr int K     = 10;
constexpr int BPB   = 4;           // one batch element per 64-lane wave; 256 thr = 4 waves
constexpr int GRID  = B / BPB;     // 4096 blocks

// Kernel 1: per-block partial sum of log-sigmoid losses -> d_ws[blockIdx.x].
//
// Layout (R4): 64 lanes per batch element, float2 per lane (64*8B = 512B = one row).
// All 12 row indices are wave-uniform -> forced to SGPRs via readfirstlane, so
// row gathers are saddr-form loads with ONE shared lane-offset VGPR. Payload is
// 12 x float2 = 24 VGPRs -> total well under 64 -> 32 waves/CU occupancy (2x the
// 32-lane/float4 layout, which needed 48 payload VGPRs + 12 vector addresses).
// This kernel is latency-bound on random row gathers: time ~ 1/(waves x loads-in-flight).
//
// NOTE (R2 lesson): do NOT add a min-waves arg to __launch_bounds__ — a register
// cap made the compiler serialize the gathers (VGPR=32 -> 118 us vs <41 us).
__global__ __launch_bounds__(256) void skipgram_partial_kernel(
    const int*   __restrict__ center_id,
    const int*   __restrict__ pos_id,
    const int*   __restrict__ neg_ids,
    const float* __restrict__ W_in,
    const float* __restrict__ W_out,
    float*       __restrict__ partial)
{
    const int tid  = threadIdx.x;
    const int lane = tid & 63;     // dim-pair index (0..63); 64 lanes x float2 = 128 = DIM
    const int w    = tid >> 6;     // wave id within block (0..3)

    // b is wave-uniform; pin it (and everything derived) to SGPRs.
    const int b = __builtin_amdgcn_readfirstlane(blockIdx.x * BPB + w);

    const int cid = __builtin_amdgcn_readfirstlane(center_id[b]);
    const int pid = __builtin_amdgcn_readfirstlane(pos_id[b]);
    int nid[K];
#pragma unroll
    for (int k = 0; k < K; ++k)
        nid[k] = __builtin_amdgcn_readfirstlane(neg_ids[b * K + k]);

    const float2 c = ((const float2*)(W_in  + (size_t)cid * DIM))[lane];
    const float2 p = ((const float2*)(W_out + (size_t)pid * DIM))[lane];

    // Sum the 10 negative rows first: neg contribution is
    // log_sigmoid(-dot(center, sum_k neg_k))  (sum over k happens before sigmoid)
    float2 ns = make_float2(0.f, 0.f);
#pragma unroll
    for (int k = 0; k < K; ++k) {
        const float2 n = ((const float2*)(W_out + (size_t)nid[k] * DIM))[lane];
        ns.x += n.x; ns.y += n.y;
    }

    float pos_partial = c.x * p.x  + c.y * p.y;
    float neg_partial = c.x * ns.x + c.y * ns.y;

    // Full 64-lane wave reduction (element spans the whole wave).
#pragma unroll
    for (int m = 32; m >= 1; m >>= 1) {
        pos_partial += __shfl_xor(pos_partial, m, 64);
        neg_partial += __shfl_xor(neg_partial, m, 64);
    }

    __shared__ float blocksum[BPB];
    if (lane == 0) {
        const float ps  = pos_partial;
        const float nsc = neg_partial;
        // stable log_sigmoid(x) = min(x,0) - log1p(exp(-|x|))
        const float lp = fminf(ps,   0.f) - log1pf(expf(-fabsf(ps)));
        const float ln = fminf(-nsc, 0.f) - log1pf(expf(-fabsf(nsc)));
        blocksum[w] = lp + ln;
    }
    __syncthreads();

    if (tid == 0) {
        float s = 0.f;
#pragma unroll
        for (int i = 0; i < BPB; ++i) s += blocksum[i];
        partial[blockIdx.x] = s;
    }
}

// Kernel 2: reduce GRID=4096 partials -> out[0] = -(total loss).
// One block of 256 threads: 4 x float4 per thread covers 4096 floats.
__global__ __launch_bounds__(256) void skipgram_reduce_kernel(
    const float* __restrict__ partial,
    float*       __restrict__ out)
{
    const int tid = threadIdx.x;
    const float4* p4 = (const float4*)partial;   // 4096 floats = 1024 float4

    float s = 0.f;
#pragma unroll
    for (int i = 0; i < 4; ++i) {
        const float4 v = p4[tid + i * 256];      // indices 0..1023
        s += v.x + v.y + v.z + v.w;
    }

    // Full 64-lane wave reduction.
#pragma unroll
    for (int m = 32; m >= 1; m >>= 1) s += __shfl_xor(s, m, 64);

    __shared__ float wsum[4];
    if ((tid & 63) == 0) wsum[tid >> 6] = s;
    __syncthreads();

    if (tid == 0) out[0] = -(wsum[0] + wsum[1] + wsum[2] + wsum[3]);
}

extern "C" void kernel_launch(void* const* d_in, const int* in_sizes, int n_in,
                              void* d_out, int out_size, void* d_ws, size_t ws_size,
                              hipStream_t stream) {
    const int*   center_id = (const int*)  d_in[0];
    const int*   pos_id    = (const int*)  d_in[1];
    const int*   neg_ids   = (const int*)  d_in[2];
    const float* W_in      = (const float*)d_in[3];
    const float* W_out     = (const float*)d_in[4];
    float*       out       = (float*)d_out;
    float*       partial   = (float*)d_ws;       // 4096 floats = 16 KB of workspace

    skipgram_partial_kernel<<<GRID, 256, 0, stream>>>(
        center_id, pos_id, neg_ids, W_in, W_out, partial);
    skipgram_reduce_kernel<<<1, 256, 0, stream>>>(partial, out);
}

// Round 5
// 123.961 us; speedup vs baseline: 1.0153x; 1.0153x over previous
//
#include <hip/hip_runtime.h>
#include <math.h>

// Problem constants (from reference)
constexpr int VOCAB = 100000;
constexpr int DIM   = 128;
constexpr int B     = 16384;
constexpr int K     = 10;
constexpr int BPB   = 8;           // batch elements per block (256 thr = 8 x 32-lane groups)
constexpr int GRID  = B / BPB;     // 2048 blocks

// ---- Session conclusions baked in (R0-R4) ----
// * The timed graph = 2x 256MiB harness poison fills (~82us @82% HBM peak) +
//   ~35-40us of harness reset() memsets/dispatch gaps + our kernels (~5-8us).
//   Calibration: R2's 118.7us kernel alone -> 243.7us total => ~43us fixed overhead.
// * Partial-kernel traffic is compulsory: 47MB HBM (unique rows) + ~53MB L3-served.
//   Both concurrency doublings (R3: 2048 blocks; R4: 64-lane/SGPR-index layout,
//   32 waves/CU) were null => kernel is a single-digit-us sliver, not the bottleneck.
// * R2 lesson: never cap VGPRs (__launch_bounds__ min-waves) — serialized the 12
//   in-flight gathers (VGPR=32, 118us). R0 lesson: no zero-kernel + atomic tail.
__global__ __launch_bounds__(256) void skipgram_partial_kernel(
    const int*   __restrict__ center_id,
    const int*   __restrict__ pos_id,
    const int*   __restrict__ neg_ids,
    const float* __restrict__ W_in,
    const float* __restrict__ W_out,
    float*       __restrict__ partial)
{
    const int tid    = threadIdx.x;
    const int lane32 = tid & 31;   // dim-group index (0..31); 32 lanes x float4 = 128 = DIM
    const int sub    = tid >> 5;   // batch element within block (0..7)
    const int b      = blockIdx.x * BPB + sub;

    // Issue all index loads up front -> addresses resolve in one memory round-trip.
    // neg_ids row starts at byte offset b*40 (8-aligned) -> 5x int2.
    const int cid = center_id[b];
    const int pid = pos_id[b];
    int nid[K];
    const int2* nrow = (const int2*)(neg_ids + b * K);
#pragma unroll
    for (int k = 0; k < K / 2; ++k) {
        const int2 v = nrow[k];
        nid[2 * k]     = v.x;
        nid[2 * k + 1] = v.y;
    }

    const float4 c = ((const float4*)(W_in  + (size_t)cid * DIM))[lane32];
    const float4 p = ((const float4*)(W_out + (size_t)pid * DIM))[lane32];

    // Sum the 10 negative rows first: neg contribution is
    // log_sigmoid(-dot(center, sum_k neg_k))  (sum over k happens before sigmoid)
    float4 ns = make_float4(0.f, 0.f, 0.f, 0.f);
#pragma unroll
    for (int k = 0; k < K; ++k) {
        const float4 n = ((const float4*)(W_out + (size_t)nid[k] * DIM))[lane32];
        ns.x += n.x; ns.y += n.y; ns.z += n.z; ns.w += n.w;
    }

    float pos_partial = c.x * p.x  + c.y * p.y  + c.z * p.z  + c.w * p.w;
    float neg_partial = c.x * ns.x + c.y * ns.y + c.z * ns.z + c.w * ns.w;

    // Reduce across the 32 lanes sharing this batch element.
    // xor masks <= 16 stay within each 32-lane half of the 64-lane wave.
#pragma unroll
    for (int m = 16; m >= 1; m >>= 1) {
        pos_partial += __shfl_xor(pos_partial, m, 64);
        neg_partial += __shfl_xor(neg_partial, m, 64);
    }

    __shared__ float blocksum[BPB];
    if (lane32 == 0) {
        const float ps  = pos_partial;
        const float nsc = neg_partial;
        // stable log_sigmoid(x) = min(x,0) - log1p(exp(-|x|))
        const float lp = fminf(ps,   0.f) - log1pf(expf(-fabsf(ps)));
        const float ln = fminf(-nsc, 0.f) - log1pf(expf(-fabsf(nsc)));
        blocksum[sub] = lp + ln;
    }
    __syncthreads();

    if (tid == 0) {
        float s = 0.f;
#pragma unroll
        for (int i = 0; i < BPB; ++i) s += blocksum[i];
        partial[blockIdx.x] = s;
    }
}

// Kernel 2: reduce GRID=2048 partials -> out[0] = -(total loss).
// One block of 256 threads: 2 x float4 per thread covers 2048 floats.
__global__ __launch_bounds__(256) void skipgram_reduce_kernel(
    const float* __restrict__ partial,
    float*       __restrict__ out)
{
    const int tid = threadIdx.x;
    const float4* p4 = (const float4*)partial;   // 2048 floats = 512 float4

    float s = 0.f;
#pragma unroll
    for (int i = 0; i < 2; ++i) {
        const float4 v = p4[tid + i * 256];      // indices 0..511
        s += v.x + v.y + v.z + v.w;
    }

    // Full 64-lane wave reduction.
#pragma unroll
    for (int m = 32; m >= 1; m >>= 1) s += __shfl_xor(s, m, 64);

    __shared__ float wsum[4];
    if ((tid & 63) == 0) wsum[tid >> 6] = s;
    __syncthreads();

    if (tid == 0) out[0] = -(wsum[0] + wsum[1] + wsum[2] + wsum[3]);
}

extern "C" void kernel_launch(void* const* d_in, const int* in_sizes, int n_in,
                              void* d_out, int out_size, void* d_ws, size_t ws_size,
                              hipStream_t stream) {
    const int*   center_id = (const int*)  d_in[0];
    const int*   pos_id    = (const int*)  d_in[1];
    const int*   neg_ids   = (const int*)  d_in[2];
    const float* W_in      = (const float*)d_in[3];
    const float* W_out     = (const float*)d_in[4];
    float*       out       = (float*)d_out;
    float*       partial   = (float*)d_ws;       // 2048 floats = 8 KB of workspace

    skipgram_partial_kernel<<<GRID, 256, 0, stream>>>(
        center_id, pos_id, neg_ids, W_in, W_out, partial);
    skipgram_reduce_kernel<<<1, 256, 0, stream>>>(partial, out);
}